// Round 1
// baseline (804.264 us; speedup 1.0000x reference)
//
#include <hip/hip_runtime.h>
#include <hip/hip_bf16.h>
#include <stdint.h>

// Problem dims (fixed by reference): B,C,F,W,H,K,S = 64,256,512,64,64,3,1
#define C_DIM 256
#define F_DIM 512
#define B_DIM 64
#define N_DIM 4096          // W*H
#define BM 128
#define BN 128
#define BK 32
#define SB_STRIDE 80        // bytes per row of transposed B tile (64 data + 16 pad)

typedef __bf16  bf16x8 __attribute__((ext_vector_type(8)));
typedef float   f32x4  __attribute__((ext_vector_type(4)));

// ---------------- prep: W2[f][c] = sum_{3x3} tanh(w + 0.5*log(eps/(1-eps))) ----------------
// tanh(w + 0.5*ln r) = (e^{2w} r - 1)/(e^{2w} r + 1) = 1 - 2/(e^{2w} r + 1); inf-safe form.
__global__ void prep_w2(const float* __restrict__ w, const float* __restrict__ eps,
                        __hip_bfloat16* __restrict__ w2) {
    int id = blockIdx.x * blockDim.x + threadIdx.x;          // [0, F*C)
    if (id >= F_DIM * C_DIM) return;
    const float* wp = w  + id * 9;
    const float* ep = eps + id * 9;
    float s = 0.f;
#pragma unroll
    for (int i = 0; i < 9; ++i) {
        float wi = wp[i], e = ep[i];
        float r = e / (1.0f - e);
        float t = __expf(2.0f * wi) * r;
        s += 1.0f - 2.0f / (t + 1.0f);
    }
    w2[id] = __float2bfloat16(s);
}

// ---------------- helpers ----------------
__device__ inline void load_lds16(const void* g, void* l) {
    __builtin_amdgcn_global_load_lds(
        (const __attribute__((address_space(1))) uint32_t*)g,
        (__attribute__((address_space(3))) uint32_t*)l, 16, 0, 0);
}

__device__ inline uint32_t pack_bf16x2(float a, float b) {
    union { __hip_bfloat162 h; uint32_t u; } c;
    c.h.x = __float2bfloat16(a);
    c.h.y = __float2bfloat16(b);
    return c.u;
}

// ---------------- GEMM: out[b][f][n] = sum_c W2[f][c] * X[b][c][n] ----------------
__global__ __launch_bounds__(256)
void gemm_kernel(const float* __restrict__ X,
                 const __hip_bfloat16* __restrict__ W2,
                 float* __restrict__ Out) {
    // sA: [m][k] bf16, 64B rows (global_load_lds-compatible, m97-proven reads)
    __shared__ __hip_bfloat16 sA[BM * BK];                 // 8 KB
    // sB: transposed X tile [n][k] bf16, 80B row stride (16B aligned, pad kills pow2)
    __shared__ unsigned char  sB[BN * SB_STRIDE];          // 10 KB

    const int tid  = threadIdx.x;
    const int lane = tid & 63;
    const int wave = tid >> 6;

    // XCD-aware swizzle: blocks {x, x+8, ...} form a per-XCD sequence with f-tile
    // fastest -> 4 blocks sharing an X tile land on the same XCD (x fetched once).
    int wid  = (blockIdx.x & 7) * 1024 + (blockIdx.x >> 3);
    int fi   = wid & 3;            // f tile   [0,4)
    int rest = wid >> 2;
    int ni   = rest & 31;          // n tile   [0,32)
    int bi   = rest >> 5;          // batch    [0,64)

    const float* Xb           = X  + (size_t)bi * C_DIM * N_DIM + ni * BN;
    const __hip_bfloat16* Ab  = W2 + fi * BM * C_DIM;
    float* Ob                 = Out + ((size_t)bi * F_DIM + (size_t)fi * BM) * N_DIM + ni * BN;

    const int bn  = tid & 127;     // n within tile (lane-consecutive -> coalesced loads)
    const int bkh = tid >> 7;      // 0/1: which half of the k-quads this thread covers

    f32x4 acc[4][4];
#pragma unroll
    for (int i = 0; i < 4; ++i)
#pragma unroll
        for (int j = 0; j < 4; ++j)
            acc[i][j] = (f32x4){0.f, 0.f, 0.f, 0.f};

    const int wm = (wave >> 1) * 64;    // wave tile origin
    const int wn = (wave & 1) * 64;
    const int l15 = lane & 15;
    const int l4  = lane >> 4;

    for (int kt = 0; kt < C_DIM; kt += BK) {
        __syncthreads();   // previous iter's frag reads done before restaging

        // ---- A tile: 8KB via 2x global_load_lds dwordx4 per thread-slot ----
#pragma unroll
        for (int j = 0; j < 2; ++j) {
            int slot = j * 256 + tid;            // 16B slots, lane-contiguous per wave
            int m  = slot >> 2;
            int k8 = slot & 3;
            const __hip_bfloat16* gp = Ab + m * C_DIM + kt + k8 * 8;
            char* lp = (char*)sA + (j * 256 + wave * 64) * 16;   // wave-uniform base
            load_lds16((const void*)gp, (void*)lp);
        }

        // ---- B tile: load fp32 (coalesced along n), cvt->bf16, transpose into LDS ----
        float xv[4][4];
#pragma unroll
        for (int i = 0; i < 4; ++i) {
            int q  = bkh + 2 * i;                // k-quad index [0,8)
            const float* xp = Xb + (size_t)(kt + 4 * q) * N_DIM + bn;
#pragma unroll
            for (int d = 0; d < 4; ++d) xv[i][d] = xp[(size_t)d * N_DIM];
        }
#pragma unroll
        for (int i = 0; i < 4; ++i) {
            int q = bkh + 2 * i;
            uint2 v;
            v.x = pack_bf16x2(xv[i][0], xv[i][1]);   // k = 4q, 4q+1
            v.y = pack_bf16x2(xv[i][2], xv[i][3]);   // k = 4q+2, 4q+3
            *(uint2*)(&sB[bn * SB_STRIDE + q * 8]) = v;
        }

        __syncthreads();   // staging complete (barrier drains vmcnt for lds-DMA)

        // ---- fragments + MFMA ----
        bf16x8 af[4], bfrag[4];
#pragma unroll
        for (int mi = 0; mi < 4; ++mi) {
            int m = wm + mi * 16 + l15;
            af[mi] = *(const bf16x8*)((const char*)sA + m * 64 + l4 * 16);
        }
#pragma unroll
        for (int nj = 0; nj < 4; ++nj) {
            int n = wn + nj * 16 + l15;
            bfrag[nj] = *(const bf16x8*)(&sB[n * SB_STRIDE + l4 * 16]);
        }
#pragma unroll
        for (int mi = 0; mi < 4; ++mi)
#pragma unroll
            for (int nj = 0; nj < 4; ++nj)
                acc[mi][nj] = __builtin_amdgcn_mfma_f32_16x16x32_bf16(
                    af[mi], bfrag[nj], acc[mi][nj], 0, 0, 0);
    }

    // ---- epilogue: C/D layout col=lane&15, row=(lane>>4)*4+r (m89-verified) ----
#pragma unroll
    for (int mi = 0; mi < 4; ++mi) {
        int mrow = wm + mi * 16 + l4 * 4;
#pragma unroll
        for (int nj = 0; nj < 4; ++nj) {
            int ncol = wn + nj * 16 + l15;
            float* op = Ob + (size_t)mrow * N_DIM + ncol;
#pragma unroll
            for (int r = 0; r < 4; ++r)
                op[(size_t)r * N_DIM] = acc[mi][nj][r];
        }
    }
}

extern "C" void kernel_launch(void* const* d_in, const int* in_sizes, int n_in,
                              void* d_out, int out_size, void* d_ws, size_t ws_size,
                              hipStream_t stream) {
    const float* x   = (const float*)d_in[0];   // [64,256,64,64]
    const float* w   = (const float*)d_in[1];   // [512,256,3,3]
    const float* eps = (const float*)d_in[2];   // [1,512,256,3,3]
    float* out       = (float*)d_out;           // [1,64,512,64,64]
    __hip_bfloat16* w2 = (__hip_bfloat16*)d_ws; // 512*256 bf16 = 256 KB scratch

    prep_w2<<<dim3((F_DIM * C_DIM + 255) / 256), dim3(256), 0, stream>>>(w, eps, w2);
    gemm_kernel<<<dim3(8192), dim3(256), 0, stream>>>(x, w2, out);
}